// Round 18
// baseline (162.403 us; speedup 1.0000x reference)
//
#include <hip/hip_runtime.h>
#include <math.h>

typedef unsigned int u32;
typedef unsigned short u16;

typedef __attribute__((ext_vector_type(8))) short bf16x8;
typedef __attribute__((ext_vector_type(4))) float f32x4;

#define NTOK 98
#define NWIN 1024

// LDS geometry for k2 (u16 units). Total 26640 u16 = 53280 B -> 3 blocks/CU.
#define XS_STR 104
#define QK_STR 40
#define P_STR  136
#define Q_BASE 13328
#define K_BASE 17808
#define VT_BASE 22288
#define LDS_U16 26640

// comb2 layout: [m(8)][hd(3)][mt(7)][r(4)][ntp(4)][lane(64)][2] bf16
#define COMB_U16 344064

__device__ __forceinline__ float bflo(u32 u){ union{u32 i; float f;} c; c.i = u<<16; return c.f; }
__device__ __forceinline__ float bfhi(u32 u){ union{u32 i; float f;} c; c.i = u & 0xffff0000u; return c.f; }
__device__ __forceinline__ u16 f2bf(float f){
  union{float f; u32 i;} c; c.f = f;
  u32 x = c.i;
  return (u16)((x + 0x7fffu + ((x>>16)&1u)) >> 16);
}

// sigmoid-GELU: v * sigma(1.702 v). |err| vs erf-GELU <= 0.02 absolute.
__device__ __forceinline__ float gelu_f(float v){
  float t = __expf(-1.702f * v);
  return v * __builtin_amdgcn_rcpf(1.f + t);
}

__device__ __forceinline__ int src_token(int win, int t){
  int b  = win >> 9;
  int wr = win & 511;
  int db = wr >> 6, hb = (wr >> 3) & 7, wb = wr & 7;
  int di = t / 49, r = t - di*49;
  int hi = r / 7,  wi = r - hi*7;
  int d = (db*2 + di + 1) & 15;
  int h = hb*7 + hi + 3; if (h >= 56) h -= 56;
  int w = wb*7 + wi + 3; if (w >= 56) w -= 56;
  return ((b*16 + d)*56 + h)*56 + w;
}

// ---------------- K0: preconvert all GEMM weights to bf16 ----------------
__global__ __launch_bounds__(256) void k0_prep(const float* __restrict__ qkvw,
    const float* __restrict__ qkvb, const float* __restrict__ pw,
    const float* __restrict__ w1, const float* __restrict__ w2,
    u16* __restrict__ Wb, float* __restrict__ bs){
  int i = blockIdx.x*256 + threadIdx.x;
  if (i < 288*96){
    float v = qkvw[i];
    if (i < 96*96) v *= 0.17677669529663687f;
    Wb[i] = f2bf(v);
  } else if (i < 288*96 + 96*96){
    Wb[i] = f2bf(pw[i - 288*96]);
  } else if (i < 288*96 + 96*96 + 384*96){
    Wb[i] = f2bf(w1[i - (288*96 + 96*96)]);
  } else if (i < 288*96 + 96*96 + 384*96 + 96*384){
    Wb[i] = f2bf(w2[i - (288*96 + 96*96 + 384*96)]);
  }
  if (i < 288){
    float v = qkvb[i];
    if (i < 96) v *= 0.17677669529663687f;
    bs[i] = v;
  }
}

// ---------------- K0b: comb2 swizzled bias+mask table (bf16, lane-major) ----------------
__global__ __launch_bounds__(256) void k0b_comb(const float* __restrict__ bias_tab,
    const int* __restrict__ rel_idx, const float* __restrict__ mask,
    u16* __restrict__ comb){
  int idx = blockIdx.x*256 + threadIdx.x;
  if (idx >= COMB_U16) return;
  int m   = idx / 43008;  int r1 = idx - m*43008;
  int hd  = r1 / 14336;   int r2 = r1 - hd*14336;
  int mt  = r2 / 2048;    int r3 = r2 - mt*2048;
  int rr  = r3 / 512;     int r4 = r3 - rr*512;
  int ntp = r4 / 128;     int r5 = r4 - ntp*128;
  int ln  = r5 >> 1;      int half = r5 & 1;
  int lg  = ln >> 4,      l15 = ln & 15;
  int nt  = ntp*2 + half;
  int i   = mt*16 + lg*4 + rr;
  int j   = nt*16 + l15;
  float v = -1e30f;
  if (i < 98 && j < 98){
    int wr = ((m>>2)&1)*448 + ((m>>1)&1)*56 + (m&1)*7;
    v = bias_tab[rel_idx[i*98+j]*3 + hd] + mask[(size_t)wr*9604 + i*98 + j];
  }
  comb[idx] = f2bf(v);
}

// ---------------- K1: LN(x2) + shift + window partition -> xn (bf16) ----------------
__global__ __launch_bounds__(256) void k1_ln(const float* __restrict__ x,
      const float* __restrict__ g, const float* __restrict__ bb, u16* __restrict__ xn){
  int wid  = (blockIdx.x << 2) + (threadIdx.x >> 6);
  int lane = threadIdx.x & 63;
  if (wid >= NWIN*NTOK) return;
  int win = wid / NTOK, t = wid - win*NTOK;
  int tok = src_token(win, t);
  const float* xp = x + (size_t)tok*192 + 96;
  float a0 = 0.f, a1 = 0.f;
  if (lane < 48){ float2 v = *(const float2*)(xp + (lane<<1)); a0 = v.x; a1 = v.y; }
  float s = a0 + a1, s2 = a0*a0 + a1*a1;
  #pragma unroll
  for (int o = 32; o; o >>= 1){ s += __shfl_xor(s, o); s2 += __shfl_xor(s2, o); }
  float mean = s * (1.f/96.f);
  float rstd = rsqrtf(s2*(1.f/96.f) - mean*mean + 1e-5f);
  if (lane < 48){
    float r0 = (a0-mean)*rstd*g[2*lane]   + bb[2*lane];
    float r1 = (a1-mean)*rstd*g[2*lane+1] + bb[2*lane+1];
    u32 pk = (u32)f2bf(r0) | ((u32)f2bf(r1) << 16);
    *(u32*)(xn + (size_t)wid*96 + (lane<<1)) = pk;
  }
}

// ---------------- K2: per (window, head) MFMA attention ----------------
// XCD grouping: j -> group=j/24, xcd=j%8, slot=(j%24)/8; win=group*8+xcd, hd=slot.
__global__ __launch_bounds__(256) void k2_attn(const u16* __restrict__ xn,
    const u16* __restrict__ Wb, const float* __restrict__ bs,
    const u16* __restrict__ comb, u16* __restrict__ attn_o){
  __shared__ __align__(16) u16 lds[LDS_U16];
  int tid  = threadIdx.x;
  int lane = tid & 63, wv = tid >> 6;
  int l15  = lane & 15, lg = lane >> 4;
  int j = blockIdx.x;
  int group = j / 24, r24 = j - group*24;
  int win = group*8 + (r24 & 7);
  int hd  = r24 >> 3;

  {
    const u32* xw = (const u32*)(xn + (size_t)win*98*96);
    u32* xs32 = (u32*)lds;
    for (int i = tid; i < 98*48; i += 256){
      int r = i/48, c = i - r*48;
      xs32[r*52 + c] = xw[i];
    }
    for (int i = tid; i < 14*52; i += 256){
      int r = 98 + i/52, c = i - (i/52)*52;
      xs32[r*52 + c] = 0;
    }
    u32* vt32 = (u32*)(lds + VT_BASE);
    for (int i = tid; i < 32*12; i += 256){
      int d = i/12, c = i - d*12;
      vt32[d*68 + 56 + c] = 0;
    }
  }
  __syncthreads();

  for (int t = wv; t < 42; t += 4){
    f32x4 acc = {0.f,0.f,0.f,0.f};
    if (t < 28){
      int tt = (t < 14) ? t : t - 14;
      int mt = tt >> 1, nt = tt & 1;
      int ch = hd*32 + nt*16 + l15 + ((t < 14) ? 0 : 96);
      const u16* wrow = Wb + ch*96 + lg*8;
      const u16* xsrow = lds + (mt*16 + l15)*XS_STR;
      #pragma unroll
      for (int ks = 0; ks < 3; ks++){
        bf16x8 a = *(const bf16x8*)(xsrow + ks*32 + lg*8);
        bf16x8 b = *(const bf16x8*)(wrow + ks*32);
        acc = __builtin_amdgcn_mfma_f32_16x16x32_bf16(a, b, acc, 0, 0, 0);
      }
      float bias = bs[ch];
      u16* dst = lds + ((t < 14) ? Q_BASE : K_BASE);
      int col = nt*16 + l15;
      int rbase = mt*16 + lg*4;
      #pragma unroll
      for (int r = 0; r < 4; r++)
        dst[(rbase+r)*QK_STR + col] = f2bf(acc[r] + bias);
    } else {
      int tt = t - 28; int mt = tt/7, nt = tt - mt*7;
      int ch = 192 + hd*32 + mt*16 + l15;
      const u16* wrow = Wb + ch*96 + lg*8;
      const u16* xsrow = lds + (nt*16 + l15)*XS_STR;
      #pragma unroll
      for (int ks = 0; ks < 3; ks++){
        bf16x8 a = *(const bf16x8*)(wrow + ks*32);
        bf16x8 b = *(const bf16x8*)(xsrow + ks*32 + lg*8);
        acc = __builtin_amdgcn_mfma_f32_16x16x32_bf16(a, b, acc, 0, 0, 0);
      }
      int dbase = mt*16 + lg*4;
      #pragma unroll
      for (int r = 0; r < 4; r++){
        float bias = bs[192 + hd*32 + dbase + r];
        lds[VT_BASE + (dbase+r)*P_STR + nt*16 + l15] = f2bf(acc[r] + bias);
      }
    }
  }
  __syncthreads();

  {
    int wr = win & 511;
    int maskid = ((wr>>6)==7)*4 + (((wr>>3)&7)==7)*2 + ((wr&7)==7);
    const u32* cb_base = (const u32*)comb + (size_t)(maskid*3 + hd)*7168 + lane;

    for (int mt = wv; mt < 7; mt += 4){
      {
        u32* p32 = (u32*)lds;
        int rmax = (mt == 6) ? 2 : 16;
        for (int i = lane; i < rmax*12; i += 64){
          int rr = i/12, c = i - rr*12;
          p32[(mt*16+rr)*68 + 56 + c] = 0;
        }
      }
      int ibase = mt*16 + lg*4;
      const u32* cbm = cb_base + mt*1024;
      float cb[4][7];
      #pragma unroll
      for (int r = 0; r < 4; r++){
        #pragma unroll
        for (int ntp = 0; ntp < 4; ntp++){
          u32 pk = cbm[(r*4 + ntp)*64];
          cb[r][2*ntp] = bflo(pk);
          if (2*ntp + 1 < 7) cb[r][2*ntp+1] = bfhi(pk);
        }
      }
      const u16* qrow = lds + Q_BASE + (mt*16 + l15)*QK_STR;
      bf16x8 a = *(const bf16x8*)(qrow + lg*8);
      f32x4 s[7];
      #pragma unroll
      for (int nt = 0; nt < 7; nt++){
        const u16* krow = lds + K_BASE + (nt*16 + l15)*QK_STR;
        bf16x8 b = *(const bf16x8*)(krow + lg*8);
        f32x4 z = {0.f,0.f,0.f,0.f};
        s[nt] = __builtin_amdgcn_mfma_f32_16x16x32_bf16(a, b, z, 0, 0, 0);
      }
      #pragma unroll
      for (int r = 0; r < 4; r++){
        int i = ibase + r;
        float sv[7];
        float mx = -3.0e38f;
        #pragma unroll
        for (int nt = 0; nt < 7; nt++){
          float v = s[nt][r] + cb[r][nt];
          sv[nt] = v; mx = fmaxf(mx, v);
        }
        #pragma unroll
        for (int off = 1; off < 16; off <<= 1) mx = fmaxf(mx, __shfl_xor(mx, off));
        float sum = 0.f;
        #pragma unroll
        for (int nt = 0; nt < 7; nt++){
          float e = __expf(sv[nt] - mx);
          sv[nt] = e; sum += e;
        }
        #pragma unroll
        for (int off = 1; off < 16; off <<= 1) sum += __shfl_xor(sum, off);
        float inv = 1.f / sum;
        if (i < 98){
          #pragma unroll
          for (int nt = 0; nt < 7; nt++)
            lds[i*P_STR + nt*16 + l15] = f2bf(sv[nt]*inv);
        }
      }
    }
  }
  __syncthreads();

  for (int t = wv; t < 14; t += 4){
    int mt = t >> 1, nt = t & 1;
    const u16* prow = lds + (mt*16 + l15)*P_STR;
    const u16* vrow = lds + VT_BASE + (nt*16 + l15)*P_STR;
    f32x4 acc = {0.f,0.f,0.f,0.f};
    #pragma unroll
    for (int ks = 0; ks < 4; ks++){
      bf16x8 a = *(const bf16x8*)(prow + ks*32 + lg*8);
      bf16x8 b = *(const bf16x8*)(vrow + ks*32 + lg*8);
      acc = __builtin_amdgcn_mfma_f32_16x16x32_bf16(a, b, acc, 0, 0, 0);
    }
    int ibase = mt*16 + lg*4;
    int d = nt*16 + l15;
    #pragma unroll
    for (int r = 0; r < 4; r++){
      int i = ibase + r;
      if (i < 98) attn_o[((size_t)win*98 + i)*96 + hd*32 + d] = f2bf(acc[r]);
    }
  }
}

// ---------------- K34: fused proj + x1 + LN + fc1 + GELU + fc2 + x2 ----------------
// 32 natural tokens/block. fc1/fc2 weights staged through LDS (padded strides,
// register double-buffered: load chunk c+1 while computing chunk c).
// LDS u16 layout (total 19264 u16 = 38528 B -> 4 blocks/CU):
//   H [0, 12544)   (fc1 out 32x392; overlays aw [0,3328), x1f [3328,9728); resf later)
//   S [12544, 19200)  stage buffer 6656 u16 (fc1 64x104 / fc2 16x392+pad; overlays yn)
//   wt_s [19200, 19264)
#define HS 392
#define X1F_U16 3328
#define YN_U16 12544
#define S_U16 12544
#define WT_U16 19200
__global__ __launch_bounds__(256, 4) void k34_projmlp(const u16* __restrict__ attn_o,
    const u16* __restrict__ Pwb, const float* __restrict__ pb,
    const float* __restrict__ g2, const float* __restrict__ b2,
    const u16* __restrict__ W1b, const float* __restrict__ b1,
    const u16* __restrict__ W2b, const float* __restrict__ bb2,
    const float* __restrict__ x, float* __restrict__ out){
  __shared__ __align__(16) u16 lds[19264];
  int tid = threadIdx.x;
  int lane = tid & 63, wv = tid >> 6;
  int l15 = lane & 15, lg = lane >> 4;
  size_t base = (size_t)blockIdx.x * 32;
  float* x1f = (float*)(lds + X1F_U16);
  float* resf = (float*)lds;
  u16* S = lds + S_U16;
  u32* S32 = (u32*)S;
  int* wt_s = (int*)(lds + WT_U16);
  int mt = wv & 1, kh = wv >> 1;

  if (tid < 32){
    int tok = (int)base + tid;
    int b = tok / 50176; int r0 = tok - b*50176;
    int d = r0 / 3136;   int r1 = r0 - d*3136;
    int h = r1 / 56;     int w = r1 - h*56;
    int dd = (d + 15) & 15;
    int db = dd >> 1, di = dd & 1;
    int hh = h - 3; if (hh < 0) hh += 56;
    int hb = hh / 7, hi = hh - hb*7;
    int ww = w - 3; if (ww < 0) ww += 56;
    int wb = ww / 7, wi = ww - wb*7;
    wt_s[tid] = (b*512 + db*64 + hb*8 + wb)*98 + di*49 + hi*7 + wi;
  }
  __syncthreads();

  // ---- stage: gather aw + coalesced x1 ----
  {
    const u32* src = (const u32*)attn_o;
    u32* aw32 = (u32*)lds;
    #pragma unroll
    for (int k = 0; k < 6; k++){
      int i = tid + k*256;
      int r = i/48, c = i - r*48;
      aw32[r*52 + c] = src[(size_t)wt_s[r]*48 + c];
    }
    #pragma unroll
    for (int k = 0; k < 3; k++){
      int i = tid + k*256;
      int tk = i/24, c4 = i - tk*24;
      float4 v = *(const float4*)(x + (base + tk)*192 + c4*4);
      *(float4*)(x1f + tk*100 + c4*4) = v;
    }
  }
  __syncthreads();

  // ---- proj (dual m-tile chains) -> x1f in place ----
  {
    const u16* a0p = lds + l15*104 + lg*8;
    const u16* a1p = a0p + 16*104;
    bf16x8 a00=*(const bf16x8*)(a0p), a01=*(const bf16x8*)(a0p+32), a02=*(const bf16x8*)(a0p+64);
    bf16x8 a10=*(const bf16x8*)(a1p), a11=*(const bf16x8*)(a1p+32), a12=*(const bf16x8*)(a1p+64);
    for (int nt = wv; nt < 6; nt += 4){
      const u16* wrow = Pwb + (nt*16 + l15)*96 + lg*8;
      bf16x8 w0=*(const bf16x8*)(wrow), w1=*(const bf16x8*)(wrow+32), w2=*(const bf16x8*)(wrow+64);
      f32x4 acc0 = {0.f,0.f,0.f,0.f}, acc1 = {0.f,0.f,0.f,0.f};
      acc0 = __builtin_amdgcn_mfma_f32_16x16x32_bf16(a00, w0, acc0, 0, 0, 0);
      acc1 = __builtin_amdgcn_mfma_f32_16x16x32_bf16(a10, w0, acc1, 0, 0, 0);
      acc0 = __builtin_amdgcn_mfma_f32_16x16x32_bf16(a01, w1, acc0, 0, 0, 0);
      acc1 = __builtin_amdgcn_mfma_f32_16x16x32_bf16(a11, w1, acc1, 0, 0, 0);
      acc0 = __builtin_amdgcn_mfma_f32_16x16x32_bf16(a02, w2, acc0, 0, 0, 0);
      acc1 = __builtin_amdgcn_mfma_f32_16x16x32_bf16(a12, w2, acc1, 0, 0, 0);
      int n = nt*16 + l15;
      float bias = pb[n];
      #pragma unroll
      for (int r = 0; r < 4; r++){
        int row = lg*4 + r;
        x1f[row*100 + n] = acc0[r] + bias + x1f[row*100 + n];
      }
      #pragma unroll
      for (int r = 0; r < 4; r++){
        int row = 16 + lg*4 + r;
        x1f[row*100 + n] = acc1[r] + bias + x1f[row*100 + n];
      }
    }
  }
  __syncthreads();

  // ---- out[0:96] writeback + LN -> yn ----
  {
    #pragma unroll
    for (int k = 0; k < 3; k++){
      int i = tid + k*256;
      int tk = i/24, c4 = i - tk*24;
      *(float4*)(out + (base + tk)*192 + c4*4) = *(const float4*)(x1f + tk*100 + c4*4);
    }
    int tk = tid >> 3, c8 = tid & 7;
    const float4* yp = (const float4*)(x1f + tk*100 + c8*12);
    float4 v4[3];
    #pragma unroll
    for (int j = 0; j < 3; j++) v4[j] = yp[j];
    float s = 0.f, s2 = 0.f;
    #pragma unroll
    for (int j = 0; j < 3; j++){
      s  += v4[j].x + v4[j].y + v4[j].z + v4[j].w;
      s2 += v4[j].x*v4[j].x + v4[j].y*v4[j].y + v4[j].z*v4[j].z + v4[j].w*v4[j].w;
    }
    s  += __shfl_xor(s, 1);  s  += __shfl_xor(s, 2);  s  += __shfl_xor(s, 4);
    s2 += __shfl_xor(s2, 1); s2 += __shfl_xor(s2, 2); s2 += __shfl_xor(s2, 4);
    float mean = s * (1.f/96.f);
    float rstd = rsqrtf(s2*(1.f/96.f) - mean*mean + 1e-5f);
    u32* dst = (u32*)(lds + YN_U16) + tk*52 + c8*6;
    const float* gp = g2 + c8*12;
    const float* bp = b2 + c8*12;
    #pragma unroll
    for (int p = 0; p < 6; p++){
      float e0 = (p & 1) ? v4[p>>1].z : v4[p>>1].x;
      float e1 = (p & 1) ? v4[p>>1].w : v4[p>>1].y;
      float r0 = (e0 - mean)*rstd*gp[2*p]   + bp[2*p];
      float r1 = (e1 - mean)*rstd*gp[2*p+1] + bp[2*p+1];
      dst[p] = (u32)f2bf(r0) | ((u32)f2bf(r1) << 16);
    }
  }
  __syncthreads();

  // ---- load fc1 A-fragments from yn; issue chunk0 weight loads ----
  bf16x8 a00, a01, a02, a10, a11, a12;
  {
    const u16* a0p = lds + YN_U16 + l15*104 + lg*8;
    const u16* a1p = a0p + 16*104;
    a00 = *(const bf16x8*)(a0p); a01 = *(const bf16x8*)(a0p+32); a02 = *(const bf16x8*)(a0p+64);
    a10 = *(const bf16x8*)(a1p); a11 = *(const bf16x8*)(a1p+32); a12 = *(const bf16x8*)(a1p+64);
  }
  const u32* w1src = (const u32*)W1b;   // chunk c: 3072 u32 at c*3072
  u32 pA[12], pB[12];
  #pragma unroll
  for (int k = 0; k < 12; k++) pA[k] = w1src[tid + k*256];
  __syncthreads();   // A-frag reads complete; S region (yn) now free

  // ---- fc1 + GELU -> H. 6 chunks, reg double-buffered, padded stride 104. ----
  #pragma unroll
  for (int cc = 0; cc < 3; cc++){
    int c = cc*2;
    // write pA -> S; issue c+1 -> pB
    #pragma unroll
    for (int k = 0; k < 12; k++){
      int i = tid + k*256;
      int row = i/48, col = i - row*48;
      S32[row*52 + col] = pA[k];
    }
    #pragma unroll
    for (int k = 0; k < 12; k++) pB[k] = w1src[(c+1)*3072 + tid + k*256];
    __syncthreads();
    {
      const u16* wrow = S + (wv*16 + l15)*104 + lg*8;
      bf16x8 w0=*(const bf16x8*)(wrow), w1=*(const bf16x8*)(wrow+32), w2=*(const bf16x8*)(wrow+64);
      f32x4 acc0 = {0.f,0.f,0.f,0.f}, acc1 = {0.f,0.f,0.f,0.f};
      acc0 = __builtin_amdgcn_mfma_f32_16x16x32_bf16(a00, w0, acc0, 0, 0, 0);
      acc1 = __builtin_amdgcn_mfma_f32_16x16x32_bf16(a10, w0, acc1, 0, 0, 0);
      acc0 = __builtin_amdgcn_mfma_f32_16x16x32_bf16(a01, w1, acc0, 0, 0, 0);
      acc1 = __builtin_amdgcn_mfma_f32_16x16x32_bf16(a11, w1, acc1, 0, 0, 0);
      acc0 = __builtin_amdgcn_mfma_f32_16x16x32_bf16(a02, w2, acc0, 0, 0, 0);
      acc1 = __builtin_amdgcn_mfma_f32_16x16x32_bf16(a12, w2, acc1, 0, 0, 0);
      int n = (c*4 + wv)*16 + l15;
      float bias = b1[n];
      #pragma unroll
      for (int r = 0; r < 4; r++)
        lds[(lg*4 + r)*HS + n] = f2bf(gelu_f(acc0[r] + bias));
      #pragma unroll
      for (int r = 0; r < 4; r++)
        lds[(16 + lg*4 + r)*HS + n] = f2bf(gelu_f(acc1[r] + bias));
    }
    __syncthreads();
    // write pB -> S; issue c+2 -> pA (last iter: issue fc2 chunk0 later)
    #pragma unroll
    for (int k = 0; k < 12; k++){
      int i = tid + k*256;
      int row = i/48, col = i - row*48;
      S32[row*52 + col] = pB[k];
    }
    if (cc < 2){
      #pragma unroll
      for (int k = 0; k < 12; k++) pA[k] = w1src[(c+2)*3072 + tid + k*256];
    } else {
      #pragma unroll
      for (int k = 0; k < 12; k++) pA[k] = ((const u32*)W2b)[tid + k*256];
    }
    __syncthreads();
    {
      const u16* wrow = S + (wv*16 + l15)*104 + lg*8;
      bf16x8 w0=*(const bf16x8*)(wrow), w1=*(const bf16x8*)(wrow+32), w2=*(const bf16x8*)(wrow+64);
      f32x4 acc0 = {0.f,0.f,0.f,0.f}, acc1 = {0.f,0.f,0.f,0.f};
      acc0 = __builtin_amdgcn_mfma_f32_16x16x32_bf16(a00, w0, acc0, 0, 0, 0);
      acc1 = __builtin_amdgcn_mfma_f32_16x16x32_bf16(a10, w0, acc1, 0, 0, 0);
      acc0 = __builtin_amdgcn_mfma_f32_16x16x32_bf16(a01, w1, acc0, 0, 0, 0);
      acc1 = __builtin_amdgcn_mfma_f32_16x16x32_bf16(a11, w1, acc1, 0, 0, 0);
      acc0 = __builtin_amdgcn_mfma_f32_16x16x32_bf16(a02, w2, acc0, 0, 0, 0);
      acc1 = __builtin_amdgcn_mfma_f32_16x16x32_bf16(a12, w2, acc1, 0, 0, 0);
      int n = ((c+1)*4 + wv)*16 + l15;
      float bias = b1[n];
      #pragma unroll
      for (int r = 0; r < 4; r++)
        lds[(lg*4 + r)*HS + n] = f2bf(gelu_f(acc0[r] + bias));
      #pragma unroll
      for (int r = 0; r < 4; r++)
        lds[(16 + lg*4 + r)*HS + n] = f2bf(gelu_f(acc1[r] + bias));
    }
    __syncthreads();
  }

  // ---- fc2: 6 chunks (16 rows, stride 392), reg double-buffered; wave=(mt,kh) ----
  const u32* w2src = (const u32*)W2b;   // chunk c: 3072 u32 at c*3072
  f32x4 res0, res1, res2, res3, res4, res5;
  #pragma unroll
  for (int cc = 0; cc < 3; cc++){
    int c = cc*2;
    // write pA (chunk c) -> S padded; issue c+1 -> pB
    #pragma unroll
    for (int k = 0; k < 12; k++){
      int i = tid + k*256;
      int row = i/192, col = i - row*192;
      S32[row*196 + col] = pA[k];
    }
    #pragma unroll
    for (int k = 0; k < 12; k++) pB[k] = w2src[(c+1)*3072 + tid + k*256];
    __syncthreads();
    {
      const u16* arow = lds + (mt*16 + l15)*HS + kh*192 + lg*8;
      const u16* wrow = S + l15*392 + kh*192 + lg*8;
      f32x4 acc = {0.f,0.f,0.f,0.f};
      #pragma unroll
      for (int ks = 0; ks < 6; ks++){
        bf16x8 xa = *(const bf16x8*)(arow + ks*32);
        bf16x8 wa = *(const bf16x8*)(wrow + ks*32);
        acc = __builtin_amdgcn_mfma_f32_16x16x32_bf16(xa, wa, acc, 0, 0, 0);
      }
      if (cc == 0) res0 = acc; else if (cc == 1) res2 = acc; else res4 = acc;
    }
    __syncthreads();
    // write pB (chunk c+1) -> S; issue c+2 -> pA
    #pragma unroll
    for (int k = 0; k < 12; k++){
      int i = tid + k*256;
      int row = i/192, col = i - row*192;
      S32[row*196 + col] = pB[k];
    }
    if (cc < 2){
      #pragma unroll
      for (int k = 0; k < 12; k++) pA[k] = w2src[(c+2)*3072 + tid + k*256];
    }
    __syncthreads();
    {
      const u16* arow = lds + (mt*16 + l15)*HS + kh*192 + lg*8;
      const u16* wrow = S + l15*392 + kh*192 + lg*8;
      f32x4 acc = {0.f,0.f,0.f,0.f};
      #pragma unroll
      for (int ks = 0; ks < 6; ks++){
        bf16x8 xa = *(const bf16x8*)(arow + ks*32);
        bf16x8 wa = *(const bf16x8*)(wrow + ks*32);
        acc = __builtin_amdgcn_mfma_f32_16x16x32_bf16(xa, wa, acc, 0, 0, 0);
      }
      if (cc == 0) res1 = acc; else if (cc == 1) res3 = acc; else res5 = acc;
    }
    __syncthreads();
  }

  // ---- combine partials into resf (overlays dead H rows) ----
  if (kh == 0){
    #pragma unroll
    for (int c = 0; c < 6; c++){
      f32x4 rc = (c==0)?res0:(c==1)?res1:(c==2)?res2:(c==3)?res3:(c==4)?res4:res5;
      int col = c*16 + l15;
      float bias = bb2[col];
      #pragma unroll
      for (int r = 0; r < 4; r++)
        resf[(mt*16 + lg*4 + r)*100 + col] = rc[r] + bias;
    }
  }
  __syncthreads();
  if (kh == 1){
    #pragma unroll
    for (int c = 0; c < 6; c++){
      f32x4 rc = (c==0)?res0:(c==1)?res1:(c==2)?res2:(c==3)?res3:(c==4)?res4:res5;
      int col = c*16 + l15;
      #pragma unroll
      for (int r = 0; r < 4; r++)
        resf[(mt*16 + lg*4 + r)*100 + col] += rc[r];
    }
  }
  __syncthreads();

  // ---- coalesced out[96:192] writeback with x2 residual ----
  {
    #pragma unroll
    for (int k = 0; k < 3; k++){
      int i = tid + k*256;
      int tk = i/24, c4 = i - tk*24;
      float4 a = *(const float4*)(resf + tk*100 + c4*4);
      float4 b = *(const float4*)(x + (base + tk)*192 + 96 + c4*4);
      float4 o; o.x = a.x + b.x; o.y = a.y + b.y; o.z = a.z + b.z; o.w = a.w + b.w;
      *(float4*)(out + (base + tk)*192 + 96 + c4*4) = o;
    }
  }
}

extern "C" void kernel_launch(void* const* d_in, const int* in_sizes, int n_in,
                              void* d_out, int out_size, void* d_ws, size_t ws_size,
                              hipStream_t stream){
  const float* x    = (const float*)d_in[0];
  const float* mask = (const float*)d_in[1];
  const int*   reli = (const int*)d_in[2];
  const float* n1g  = (const float*)d_in[3];
  const float* n1b  = (const float*)d_in[4];
  const float* qkvw = (const float*)d_in[5];
  const float* qkvb = (const float*)d_in[6];
  const float* btab = (const float*)d_in[7];
  const float* pw   = (const float*)d_in[8];
  const float* pb   = (const float*)d_in[9];
  const float* n2g  = (const float*)d_in[10];
  const float* n2b  = (const float*)d_in[11];
  const float* w1   = (const float*)d_in[12];
  const float* b1   = (const float*)d_in[13];
  const float* w2   = (const float*)d_in[14];
  const float* b2   = (const float*)d_in[15];
  float* out = (float*)d_out;

  u16* xn   = (u16*)d_ws;                          // 1024*98*96 bf16
  u16* attn = xn + (size_t)NWIN*98*96;             // same size
  u16* Wb   = attn + (size_t)NWIN*98*96;           // qkv 288*96
  u16* Pwb  = Wb + 288*96;                         // 96*96
  u16* W1b  = Pwb + 96*96;                         // 384*96
  u16* W2b  = W1b + 384*96;                        // 96*384
  float* bsc = (float*)(W2b + 96*384);             // 288 f32
  u16* comb = (u16*)(bsc + 288);                   // comb2: 344064 bf16

  k0_prep<<<432,   256, 0, stream>>>(qkvw, qkvb, pw, w1, w2, Wb, bsc);
  k0b_comb<<<1344, 256, 0, stream>>>(btab, reli, mask, comb);
  k1_ln  <<<25088, 256, 0, stream>>>(x, n1g, n1b, xn);
  k2_attn<<<3072,  256, 0, stream>>>(xn, Wb, bsc, comb, attn);
  k34_projmlp<<<3136, 256, 0, stream>>>(attn, Pwb, pb, n2g, n2b,
                                        W1b, b1, W2b, b2, x, out);
}

// Round 19
// 145.366 us; speedup vs baseline: 1.1172x; 1.1172x over previous
//
#include <hip/hip_runtime.h>
#include <math.h>

typedef unsigned int u32;
typedef unsigned short u16;

typedef __attribute__((ext_vector_type(8))) short bf16x8;
typedef __attribute__((ext_vector_type(4))) float f32x4;

#define NTOK 98
#define NWIN 1024

// LDS geometry for k2 (u16 units). Total 26640 u16 = 53280 B -> 3 blocks/CU.
#define XS_STR 104
#define QK_STR 40
#define P_STR  136
#define Q_BASE 13328
#define K_BASE 17808
#define VT_BASE 22288
#define LDS_U16 26640

// comb2 layout: [m(8)][hd(3)][mt(7)][r(4)][ntp(4)][lane(64)][2] bf16
#define COMB_U16 344064

__device__ __forceinline__ float bflo(u32 u){ union{u32 i; float f;} c; c.i = u<<16; return c.f; }
__device__ __forceinline__ float bfhi(u32 u){ union{u32 i; float f;} c; c.i = u & 0xffff0000u; return c.f; }
__device__ __forceinline__ u16 f2bf(float f){
  union{float f; u32 i;} c; c.f = f;
  u32 x = c.i;
  return (u16)((x + 0x7fffu + ((x>>16)&1u)) >> 16);
}

// sigmoid-GELU: v * sigma(1.702 v). |err| vs erf-GELU <= 0.02 absolute.
__device__ __forceinline__ float gelu_f(float v){
  float t = __expf(-1.702f * v);
  return v * __builtin_amdgcn_rcpf(1.f + t);
}

__device__ __forceinline__ int src_token(int win, int t){
  int b  = win >> 9;
  int wr = win & 511;
  int db = wr >> 6, hb = (wr >> 3) & 7, wb = wr & 7;
  int di = t / 49, r = t - di*49;
  int hi = r / 7,  wi = r - hi*7;
  int d = (db*2 + di + 1) & 15;
  int h = hb*7 + hi + 3; if (h >= 56) h -= 56;
  int w = wb*7 + wi + 3; if (w >= 56) w -= 56;
  return ((b*16 + d)*56 + h)*56 + w;
}

// ---------------- K0: preconvert all GEMM weights to bf16 ----------------
__global__ __launch_bounds__(256) void k0_prep(const float* __restrict__ qkvw,
    const float* __restrict__ qkvb, const float* __restrict__ pw,
    const float* __restrict__ w1, const float* __restrict__ w2,
    u16* __restrict__ Wb, float* __restrict__ bs){
  int i = blockIdx.x*256 + threadIdx.x;
  if (i < 288*96){
    float v = qkvw[i];
    if (i < 96*96) v *= 0.17677669529663687f;
    Wb[i] = f2bf(v);
  } else if (i < 288*96 + 96*96){
    Wb[i] = f2bf(pw[i - 288*96]);
  } else if (i < 288*96 + 96*96 + 384*96){
    Wb[i] = f2bf(w1[i - (288*96 + 96*96)]);
  } else if (i < 288*96 + 96*96 + 384*96 + 96*384){
    Wb[i] = f2bf(w2[i - (288*96 + 96*96 + 384*96)]);
  }
  if (i < 288){
    float v = qkvb[i];
    if (i < 96) v *= 0.17677669529663687f;
    bs[i] = v;
  }
}

// ---------------- K0b: comb2 swizzled bias+mask table (bf16, lane-major) ----------------
__global__ __launch_bounds__(256) void k0b_comb(const float* __restrict__ bias_tab,
    const int* __restrict__ rel_idx, const float* __restrict__ mask,
    u16* __restrict__ comb){
  int idx = blockIdx.x*256 + threadIdx.x;
  if (idx >= COMB_U16) return;
  int m   = idx / 43008;  int r1 = idx - m*43008;
  int hd  = r1 / 14336;   int r2 = r1 - hd*14336;
  int mt  = r2 / 2048;    int r3 = r2 - mt*2048;
  int rr  = r3 / 512;     int r4 = r3 - rr*512;
  int ntp = r4 / 128;     int r5 = r4 - ntp*128;
  int ln  = r5 >> 1;      int half = r5 & 1;
  int lg  = ln >> 4,      l15 = ln & 15;
  int nt  = ntp*2 + half;
  int i   = mt*16 + lg*4 + rr;
  int j   = nt*16 + l15;
  float v = -1e30f;
  if (i < 98 && j < 98){
    int wr = ((m>>2)&1)*448 + ((m>>1)&1)*56 + (m&1)*7;
    v = bias_tab[rel_idx[i*98+j]*3 + hd] + mask[(size_t)wr*9604 + i*98 + j];
  }
  comb[idx] = f2bf(v);
}

// ---------------- K1: LN(x2) + shift + window partition -> xn (bf16) ----------------
__global__ __launch_bounds__(256) void k1_ln(const float* __restrict__ x,
      const float* __restrict__ g, const float* __restrict__ bb, u16* __restrict__ xn){
  int wid  = (blockIdx.x << 2) + (threadIdx.x >> 6);
  int lane = threadIdx.x & 63;
  if (wid >= NWIN*NTOK) return;
  int win = wid / NTOK, t = wid - win*NTOK;
  int tok = src_token(win, t);
  const float* xp = x + (size_t)tok*192 + 96;
  float a0 = 0.f, a1 = 0.f;
  if (lane < 48){ float2 v = *(const float2*)(xp + (lane<<1)); a0 = v.x; a1 = v.y; }
  float s = a0 + a1, s2 = a0*a0 + a1*a1;
  #pragma unroll
  for (int o = 32; o; o >>= 1){ s += __shfl_xor(s, o); s2 += __shfl_xor(s2, o); }
  float mean = s * (1.f/96.f);
  float rstd = rsqrtf(s2*(1.f/96.f) - mean*mean + 1e-5f);
  if (lane < 48){
    float r0 = (a0-mean)*rstd*g[2*lane]   + bb[2*lane];
    float r1 = (a1-mean)*rstd*g[2*lane+1] + bb[2*lane+1];
    u32 pk = (u32)f2bf(r0) | ((u32)f2bf(r1) << 16);
    *(u32*)(xn + (size_t)wid*96 + (lane<<1)) = pk;
  }
}

// ---------------- K2: per (window, head) MFMA attention ----------------
// XCD grouping: j -> group=j/24, xcd=j%8, slot=(j%24)/8; win=group*8+xcd, hd=slot.
// QKV phase restructured: wave owns a fixed weight column -> weight frags
// hoisted ONCE per wave (6 loads) instead of per tile (~33 loads).
__global__ __launch_bounds__(256) void k2_attn(const u16* __restrict__ xn,
    const u16* __restrict__ Wb, const float* __restrict__ bs,
    const u16* __restrict__ comb, u16* __restrict__ attn_o){
  __shared__ __align__(16) u16 lds[LDS_U16];
  int tid  = threadIdx.x;
  int lane = tid & 63, wv = tid >> 6;
  int l15  = lane & 15, lg = lane >> 4;
  int j = blockIdx.x;
  int group = j / 24, r24 = j - group*24;
  int win = group*8 + (r24 & 7);
  int hd  = r24 >> 3;

  // ---- stage xs (98x96 bf16, stride 104) + zero pads ----
  {
    const u32* xw = (const u32*)(xn + (size_t)win*98*96);
    u32* xs32 = (u32*)lds;
    for (int i = tid; i < 98*48; i += 256){
      int r = i/48, c = i - r*48;
      xs32[r*52 + c] = xw[i];
    }
    for (int i = tid; i < 14*52; i += 256){
      int r = 98 + i/52, c = i - (i/52)*52;
      xs32[r*52 + c] = 0;
    }
    u32* vt32 = (u32*)(lds + VT_BASE);
    for (int i = tid; i < 32*12; i += 256){
      int d = i/12, c = i - d*12;
      vt32[d*68 + 56 + c] = 0;
    }
  }
  __syncthreads();

  // ---- QKV GEMM, hoisted weights ----
  // Phase A: q (waves 0,1) and k (waves 2,3); wave's nt = wv&1, 7 mt tiles.
  {
    int isk = wv >> 1;
    int nt  = wv & 1;
    int ch  = hd*32 + nt*16 + l15 + (isk ? 96 : 0);
    const u16* wrow = Wb + ch*96 + lg*8;
    bf16x8 b0 = *(const bf16x8*)(wrow);
    bf16x8 b1 = *(const bf16x8*)(wrow + 32);
    bf16x8 b2 = *(const bf16x8*)(wrow + 64);
    float bias = bs[ch];
    u16* dst = lds + (isk ? K_BASE : Q_BASE);
    int col = nt*16 + l15;
    #pragma unroll
    for (int mt = 0; mt < 7; mt++){
      const u16* xsrow = lds + (mt*16 + l15)*XS_STR + lg*8;
      f32x4 acc = {0.f,0.f,0.f,0.f};
      acc = __builtin_amdgcn_mfma_f32_16x16x32_bf16(*(const bf16x8*)(xsrow),      b0, acc, 0, 0, 0);
      acc = __builtin_amdgcn_mfma_f32_16x16x32_bf16(*(const bf16x8*)(xsrow + 32), b1, acc, 0, 0, 0);
      acc = __builtin_amdgcn_mfma_f32_16x16x32_bf16(*(const bf16x8*)(xsrow + 64), b2, acc, 0, 0, 0);
      int rbase = mt*16 + lg*4;
      #pragma unroll
      for (int r = 0; r < 4; r++)
        dst[(rbase+r)*QK_STR + col] = f2bf(acc[r] + bias);
    }
  }
  // Phase B: vT = Wv x xs^T. Wave's d-group mtv = wv&1; token-groups nt strided.
  {
    int mtv = wv & 1;
    int ch = 192 + hd*32 + mtv*16 + l15;
    const u16* wrow = Wb + ch*96 + lg*8;
    bf16x8 a0 = *(const bf16x8*)(wrow);
    bf16x8 a1 = *(const bf16x8*)(wrow + 32);
    bf16x8 a2 = *(const bf16x8*)(wrow + 64);
    int dbase = mtv*16 + lg*4;
    float bias[4];
    #pragma unroll
    for (int r = 0; r < 4; r++) bias[r] = bs[192 + hd*32 + dbase + r];
    for (int nt = (wv >> 1); nt < 7; nt += 2){
      const u16* xsrow = lds + (nt*16 + l15)*XS_STR + lg*8;
      f32x4 acc = {0.f,0.f,0.f,0.f};
      acc = __builtin_amdgcn_mfma_f32_16x16x32_bf16(a0, *(const bf16x8*)(xsrow),      acc, 0, 0, 0);
      acc = __builtin_amdgcn_mfma_f32_16x16x32_bf16(a1, *(const bf16x8*)(xsrow + 32), acc, 0, 0, 0);
      acc = __builtin_amdgcn_mfma_f32_16x16x32_bf16(a2, *(const bf16x8*)(xsrow + 64), acc, 0, 0, 0);
      #pragma unroll
      for (int r = 0; r < 4; r++)
        lds[VT_BASE + (dbase+r)*P_STR + nt*16 + l15] = f2bf(acc[r] + bias[r]);
    }
  }
  __syncthreads();

  // ---- S = q k^T + comb2 (coalesced u32 loads), softmax, P -> LDS ----
  {
    int wr = win & 511;
    int maskid = ((wr>>6)==7)*4 + (((wr>>3)&7)==7)*2 + ((wr&7)==7);
    const u32* cb_base = (const u32*)comb + (size_t)(maskid*3 + hd)*7168 + lane;

    for (int mt = wv; mt < 7; mt += 4){
      {
        u32* p32 = (u32*)lds;
        int rmax = (mt == 6) ? 2 : 16;
        for (int i = lane; i < rmax*12; i += 64){
          int rr = i/12, c = i - rr*12;
          p32[(mt*16+rr)*68 + 56 + c] = 0;
        }
      }
      int ibase = mt*16 + lg*4;
      const u32* cbm = cb_base + mt*1024;
      float cb[4][7];
      #pragma unroll
      for (int r = 0; r < 4; r++){
        #pragma unroll
        for (int ntp = 0; ntp < 4; ntp++){
          u32 pk = cbm[(r*4 + ntp)*64];
          cb[r][2*ntp] = bflo(pk);
          if (2*ntp + 1 < 7) cb[r][2*ntp+1] = bfhi(pk);
        }
      }
      const u16* qrow = lds + Q_BASE + (mt*16 + l15)*QK_STR;
      bf16x8 a = *(const bf16x8*)(qrow + lg*8);
      f32x4 s[7];
      #pragma unroll
      for (int nt = 0; nt < 7; nt++){
        const u16* krow = lds + K_BASE + (nt*16 + l15)*QK_STR;
        bf16x8 b = *(const bf16x8*)(krow + lg*8);
        f32x4 z = {0.f,0.f,0.f,0.f};
        s[nt] = __builtin_amdgcn_mfma_f32_16x16x32_bf16(a, b, z, 0, 0, 0);
      }
      #pragma unroll
      for (int r = 0; r < 4; r++){
        int i = ibase + r;
        float sv[7];
        float mx = -3.0e38f;
        #pragma unroll
        for (int nt = 0; nt < 7; nt++){
          float v = s[nt][r] + cb[r][nt];
          sv[nt] = v; mx = fmaxf(mx, v);
        }
        #pragma unroll
        for (int off = 1; off < 16; off <<= 1) mx = fmaxf(mx, __shfl_xor(mx, off));
        float sum = 0.f;
        #pragma unroll
        for (int nt = 0; nt < 7; nt++){
          float e = __expf(sv[nt] - mx);
          sv[nt] = e; sum += e;
        }
        #pragma unroll
        for (int off = 1; off < 16; off <<= 1) sum += __shfl_xor(sum, off);
        float inv = 1.f / sum;
        if (i < 98){
          #pragma unroll
          for (int nt = 0; nt < 7; nt++)
            lds[i*P_STR + nt*16 + l15] = f2bf(sv[nt]*inv);
        }
      }
    }
  }
  __syncthreads();

  // ---- O = P V : 14 tiles, K=128 in 4 steps ----
  for (int t = wv; t < 14; t += 4){
    int mt = t >> 1, nt = t & 1;
    const u16* prow = lds + (mt*16 + l15)*P_STR;
    const u16* vrow = lds + VT_BASE + (nt*16 + l15)*P_STR;
    f32x4 acc = {0.f,0.f,0.f,0.f};
    #pragma unroll
    for (int ks = 0; ks < 4; ks++){
      bf16x8 a = *(const bf16x8*)(prow + ks*32 + lg*8);
      bf16x8 b = *(const bf16x8*)(vrow + ks*32 + lg*8);
      acc = __builtin_amdgcn_mfma_f32_16x16x32_bf16(a, b, acc, 0, 0, 0);
    }
    int ibase = mt*16 + lg*4;
    int d = nt*16 + l15;
    #pragma unroll
    for (int r = 0; r < 4; r++){
      int i = ibase + r;
      if (i < 98) attn_o[((size_t)win*98 + i)*96 + hd*32 + d] = f2bf(acc[r]);
    }
  }
}

// ---------------- K34: fused proj + x1 + LN + fc1 + GELU + fc2 + x2 ----------------
// 32 natural tokens/block. fc1/fc2 weights staged through LDS (padded strides,
// register double-buffered: load chunk c+1 while computing chunk c).
#define HS 392
#define X1F_U16 3328
#define YN_U16 12544
#define S_U16 12544
#define WT_U16 19200
__global__ __launch_bounds__(256, 4) void k34_projmlp(const u16* __restrict__ attn_o,
    const u16* __restrict__ Pwb, const float* __restrict__ pb,
    const float* __restrict__ g2, const float* __restrict__ b2,
    const u16* __restrict__ W1b, const float* __restrict__ b1,
    const u16* __restrict__ W2b, const float* __restrict__ bb2,
    const float* __restrict__ x, float* __restrict__ out){
  __shared__ __align__(16) u16 lds[19264];
  int tid = threadIdx.x;
  int lane = tid & 63, wv = tid >> 6;
  int l15 = lane & 15, lg = lane >> 4;
  size_t base = (size_t)blockIdx.x * 32;
  float* x1f = (float*)(lds + X1F_U16);
  float* resf = (float*)lds;
  u16* S = lds + S_U16;
  u32* S32 = (u32*)S;
  int* wt_s = (int*)(lds + WT_U16);
  int mt = wv & 1, kh = wv >> 1;

  if (tid < 32){
    int tok = (int)base + tid;
    int b = tok / 50176; int r0 = tok - b*50176;
    int d = r0 / 3136;   int r1 = r0 - d*3136;
    int h = r1 / 56;     int w = r1 - h*56;
    int dd = (d + 15) & 15;
    int db = dd >> 1, di = dd & 1;
    int hh = h - 3; if (hh < 0) hh += 56;
    int hb = hh / 7, hi = hh - hb*7;
    int ww = w - 3; if (ww < 0) ww += 56;
    int wb = ww / 7, wi = ww - wb*7;
    wt_s[tid] = (b*512 + db*64 + hb*8 + wb)*98 + di*49 + hi*7 + wi;
  }
  __syncthreads();

  // ---- stage: gather aw + coalesced x1 ----
  {
    const u32* src = (const u32*)attn_o;
    u32* aw32 = (u32*)lds;
    #pragma unroll
    for (int k = 0; k < 6; k++){
      int i = tid + k*256;
      int r = i/48, c = i - r*48;
      aw32[r*52 + c] = src[(size_t)wt_s[r]*48 + c];
    }
    #pragma unroll
    for (int k = 0; k < 3; k++){
      int i = tid + k*256;
      int tk = i/24, c4 = i - tk*24;
      float4 v = *(const float4*)(x + (base + tk)*192 + c4*4);
      *(float4*)(x1f + tk*100 + c4*4) = v;
    }
  }
  __syncthreads();

  // ---- proj (dual m-tile chains) -> x1f in place ----
  {
    const u16* a0p = lds + l15*104 + lg*8;
    const u16* a1p = a0p + 16*104;
    bf16x8 a00=*(const bf16x8*)(a0p), a01=*(const bf16x8*)(a0p+32), a02=*(const bf16x8*)(a0p+64);
    bf16x8 a10=*(const bf16x8*)(a1p), a11=*(const bf16x8*)(a1p+32), a12=*(const bf16x8*)(a1p+64);
    for (int nt = wv; nt < 6; nt += 4){
      const u16* wrow = Pwb + (nt*16 + l15)*96 + lg*8;
      bf16x8 w0=*(const bf16x8*)(wrow), w1=*(const bf16x8*)(wrow+32), w2=*(const bf16x8*)(wrow+64);
      f32x4 acc0 = {0.f,0.f,0.f,0.f}, acc1 = {0.f,0.f,0.f,0.f};
      acc0 = __builtin_amdgcn_mfma_f32_16x16x32_bf16(a00, w0, acc0, 0, 0, 0);
      acc1 = __builtin_amdgcn_mfma_f32_16x16x32_bf16(a10, w0, acc1, 0, 0, 0);
      acc0 = __builtin_amdgcn_mfma_f32_16x16x32_bf16(a01, w1, acc0, 0, 0, 0);
      acc1 = __builtin_amdgcn_mfma_f32_16x16x32_bf16(a11, w1, acc1, 0, 0, 0);
      acc0 = __builtin_amdgcn_mfma_f32_16x16x32_bf16(a02, w2, acc0, 0, 0, 0);
      acc1 = __builtin_amdgcn_mfma_f32_16x16x32_bf16(a12, w2, acc1, 0, 0, 0);
      int n = nt*16 + l15;
      float bias = pb[n];
      #pragma unroll
      for (int r = 0; r < 4; r++){
        int row = lg*4 + r;
        x1f[row*100 + n] = acc0[r] + bias + x1f[row*100 + n];
      }
      #pragma unroll
      for (int r = 0; r < 4; r++){
        int row = 16 + lg*4 + r;
        x1f[row*100 + n] = acc1[r] + bias + x1f[row*100 + n];
      }
    }
  }
  __syncthreads();

  // ---- out[0:96] writeback + LN -> yn ----
  {
    #pragma unroll
    for (int k = 0; k < 3; k++){
      int i = tid + k*256;
      int tk = i/24, c4 = i - tk*24;
      *(float4*)(out + (base + tk)*192 + c4*4) = *(const float4*)(x1f + tk*100 + c4*4);
    }
    int tk = tid >> 3, c8 = tid & 7;
    const float4* yp = (const float4*)(x1f + tk*100 + c8*12);
    float4 v4[3];
    #pragma unroll
    for (int j = 0; j < 3; j++) v4[j] = yp[j];
    float s = 0.f, s2 = 0.f;
    #pragma unroll
    for (int j = 0; j < 3; j++){
      s  += v4[j].x + v4[j].y + v4[j].z + v4[j].w;
      s2 += v4[j].x*v4[j].x + v4[j].y*v4[j].y + v4[j].z*v4[j].z + v4[j].w*v4[j].w;
    }
    s  += __shfl_xor(s, 1);  s  += __shfl_xor(s, 2);  s  += __shfl_xor(s, 4);
    s2 += __shfl_xor(s2, 1); s2 += __shfl_xor(s2, 2); s2 += __shfl_xor(s2, 4);
    float mean = s * (1.f/96.f);
    float rstd = rsqrtf(s2*(1.f/96.f) - mean*mean + 1e-5f);
    u32* dst = (u32*)(lds + YN_U16) + tk*52 + c8*6;
    const float* gp = g2 + c8*12;
    const float* bp = b2 + c8*12;
    #pragma unroll
    for (int p = 0; p < 6; p++){
      float e0 = (p & 1) ? v4[p>>1].z : v4[p>>1].x;
      float e1 = (p & 1) ? v4[p>>1].w : v4[p>>1].y;
      float r0 = (e0 - mean)*rstd*gp[2*p]   + bp[2*p];
      float r1 = (e1 - mean)*rstd*gp[2*p+1] + bp[2*p+1];
      dst[p] = (u32)f2bf(r0) | ((u32)f2bf(r1) << 16);
    }
  }
  __syncthreads();

  // ---- load fc1 A-fragments from yn; issue chunk0 weight loads ----
  bf16x8 a00, a01, a02, a10, a11, a12;
  {
    const u16* a0p = lds + YN_U16 + l15*104 + lg*8;
    const u16* a1p = a0p + 16*104;
    a00 = *(const bf16x8*)(a0p); a01 = *(const bf16x8*)(a0p+32); a02 = *(const bf16x8*)(a0p+64);
    a10 = *(const bf16x8*)(a1p); a11 = *(const bf16x8*)(a1p+32); a12 = *(const bf16x8*)(a1p+64);
  }
  const u32* w1src = (const u32*)W1b;
  u32 pA[12], pB[12];
  #pragma unroll
  for (int k = 0; k < 12; k++) pA[k] = w1src[tid + k*256];
  __syncthreads();

  // ---- fc1 + GELU -> H. 6 chunks, reg double-buffered, padded stride 104. ----
  #pragma unroll
  for (int cc = 0; cc < 3; cc++){
    int c = cc*2;
    #pragma unroll
    for (int k = 0; k < 12; k++){
      int i = tid + k*256;
      int row = i/48, col = i - row*48;
      S32[row*52 + col] = pA[k];
    }
    #pragma unroll
    for (int k = 0; k < 12; k++) pB[k] = w1src[(c+1)*3072 + tid + k*256];
    __syncthreads();
    {
      const u16* wrow = S + (wv*16 + l15)*104 + lg*8;
      bf16x8 w0=*(const bf16x8*)(wrow), w1=*(const bf16x8*)(wrow+32), w2=*(const bf16x8*)(wrow+64);
      f32x4 acc0 = {0.f,0.f,0.f,0.f}, acc1 = {0.f,0.f,0.f,0.f};
      acc0 = __builtin_amdgcn_mfma_f32_16x16x32_bf16(a00, w0, acc0, 0, 0, 0);
      acc1 = __builtin_amdgcn_mfma_f32_16x16x32_bf16(a10, w0, acc1, 0, 0, 0);
      acc0 = __builtin_amdgcn_mfma_f32_16x16x32_bf16(a01, w1, acc0, 0, 0, 0);
      acc1 = __builtin_amdgcn_mfma_f32_16x16x32_bf16(a11, w1, acc1, 0, 0, 0);
      acc0 = __builtin_amdgcn_mfma_f32_16x16x32_bf16(a02, w2, acc0, 0, 0, 0);
      acc1 = __builtin_amdgcn_mfma_f32_16x16x32_bf16(a12, w2, acc1, 0, 0, 0);
      int n = (c*4 + wv)*16 + l15;
      float bias = b1[n];
      #pragma unroll
      for (int r = 0; r < 4; r++)
        lds[(lg*4 + r)*HS + n] = f2bf(gelu_f(acc0[r] + bias));
      #pragma unroll
      for (int r = 0; r < 4; r++)
        lds[(16 + lg*4 + r)*HS + n] = f2bf(gelu_f(acc1[r] + bias));
    }
    __syncthreads();
    #pragma unroll
    for (int k = 0; k < 12; k++){
      int i = tid + k*256;
      int row = i/48, col = i - row*48;
      S32[row*52 + col] = pB[k];
    }
    if (cc < 2){
      #pragma unroll
      for (int k = 0; k < 12; k++) pA[k] = w1src[(c+2)*3072 + tid + k*256];
    } else {
      #pragma unroll
      for (int k = 0; k < 12; k++) pA[k] = ((const u32*)W2b)[tid + k*256];
    }
    __syncthreads();
    {
      const u16* wrow = S + (wv*16 + l15)*104 + lg*8;
      bf16x8 w0=*(const bf16x8*)(wrow), w1=*(const bf16x8*)(wrow+32), w2=*(const bf16x8*)(wrow+64);
      f32x4 acc0 = {0.f,0.f,0.f,0.f}, acc1 = {0.f,0.f,0.f,0.f};
      acc0 = __builtin_amdgcn_mfma_f32_16x16x32_bf16(a00, w0, acc0, 0, 0, 0);
      acc1 = __builtin_amdgcn_mfma_f32_16x16x32_bf16(a10, w0, acc1, 0, 0, 0);
      acc0 = __builtin_amdgcn_mfma_f32_16x16x32_bf16(a01, w1, acc0, 0, 0, 0);
      acc1 = __builtin_amdgcn_mfma_f32_16x16x32_bf16(a11, w1, acc1, 0, 0, 0);
      acc0 = __builtin_amdgcn_mfma_f32_16x16x32_bf16(a02, w2, acc0, 0, 0, 0);
      acc1 = __builtin_amdgcn_mfma_f32_16x16x32_bf16(a12, w2, acc1, 0, 0, 0);
      int n = ((c+1)*4 + wv)*16 + l15;
      float bias = b1[n];
      #pragma unroll
      for (int r = 0; r < 4; r++)
        lds[(lg*4 + r)*HS + n] = f2bf(gelu_f(acc0[r] + bias));
      #pragma unroll
      for (int r = 0; r < 4; r++)
        lds[(16 + lg*4 + r)*HS + n] = f2bf(gelu_f(acc1[r] + bias));
    }
    __syncthreads();
  }

  // ---- fc2: 6 chunks (16 rows, stride 392), reg double-buffered; wave=(mt,kh) ----
  const u32* w2src = (const u32*)W2b;
  f32x4 res0, res1, res2, res3, res4, res5;
  #pragma unroll
  for (int cc = 0; cc < 3; cc++){
    int c = cc*2;
    #pragma unroll
    for (int k = 0; k < 12; k++){
      int i = tid + k*256;
      int row = i/192, col = i - row*192;
      S32[row*196 + col] = pA[k];
    }
    #pragma unroll
    for (int k = 0; k < 12; k++) pB[k] = w2src[(c+1)*3072 + tid + k*256];
    __syncthreads();
    {
      const u16* arow = lds + (mt*16 + l15)*HS + kh*192 + lg*8;
      const u16* wrow = S + l15*392 + kh*192 + lg*8;
      f32x4 acc = {0.f,0.f,0.f,0.f};
      #pragma unroll
      for (int ks = 0; ks < 6; ks++){
        bf16x8 xa = *(const bf16x8*)(arow + ks*32);
        bf16x8 wa = *(const bf16x8*)(wrow + ks*32);
        acc = __builtin_amdgcn_mfma_f32_16x16x32_bf16(xa, wa, acc, 0, 0, 0);
      }
      if (cc == 0) res0 = acc; else if (cc == 1) res2 = acc; else res4 = acc;
    }
    __syncthreads();
    #pragma unroll
    for (int k = 0; k < 12; k++){
      int i = tid + k*256;
      int row = i/192, col = i - row*192;
      S32[row*196 + col] = pB[k];
    }
    if (cc < 2){
      #pragma unroll
      for (int k = 0; k < 12; k++) pA[k] = w2src[(c+2)*3072 + tid + k*256];
    }
    __syncthreads();
    {
      const u16* arow = lds + (mt*16 + l15)*HS + kh*192 + lg*8;
      const u16* wrow = S + l15*392 + kh*192 + lg*8;
      f32x4 acc = {0.f,0.f,0.f,0.f};
      #pragma unroll
      for (int ks = 0; ks < 6; ks++){
        bf16x8 xa = *(const bf16x8*)(arow + ks*32);
        bf16x8 wa = *(const bf16x8*)(wrow + ks*32);
        acc = __builtin_amdgcn_mfma_f32_16x16x32_bf16(xa, wa, acc, 0, 0, 0);
      }
      if (cc == 0) res1 = acc; else if (cc == 1) res3 = acc; else res5 = acc;
    }
    __syncthreads();
  }

  // ---- combine partials into resf (overlays dead H rows) ----
  if (kh == 0){
    #pragma unroll
    for (int c = 0; c < 6; c++){
      f32x4 rc = (c==0)?res0:(c==1)?res1:(c==2)?res2:(c==3)?res3:(c==4)?res4:res5;
      int col = c*16 + l15;
      float bias = bb2[col];
      #pragma unroll
      for (int r = 0; r < 4; r++)
        resf[(mt*16 + lg*4 + r)*100 + col] = rc[r] + bias;
    }
  }
  __syncthreads();
  if (kh == 1){
    #pragma unroll
    for (int c = 0; c < 6; c++){
      f32x4 rc = (c==0)?res0:(c==1)?res1:(c==2)?res2:(c==3)?res3:(c==4)?res4:res5;
      int col = c*16 + l15;
      #pragma unroll
      for (int r = 0; r < 4; r++)
        resf[(mt*16 + lg*4 + r)*100 + col] += rc[r];
    }
  }
  __syncthreads();

  // ---- coalesced out[96:192] writeback with x2 residual ----
  {
    #pragma unroll
    for (int k = 0; k < 3; k++){
      int i = tid + k*256;
      int tk = i/24, c4 = i - tk*24;
      float4 a = *(const float4*)(resf + tk*100 + c4*4);
      float4 b = *(const float4*)(x + (base + tk)*192 + 96 + c4*4);
      float4 o; o.x = a.x + b.x; o.y = a.y + b.y; o.z = a.z + b.z; o.w = a.w + b.w;
      *(float4*)(out + (base + tk)*192 + 96 + c4*4) = o;
    }
  }
}

extern "C" void kernel_launch(void* const* d_in, const int* in_sizes, int n_in,
                              void* d_out, int out_size, void* d_ws, size_t ws_size,
                              hipStream_t stream){
  const float* x    = (const float*)d_in[0];
  const float* mask = (const float*)d_in[1];
  const int*   reli = (const int*)d_in[2];
  const float* n1g  = (const float*)d_in[3];
  const float* n1b  = (const float*)d_in[4];
  const float* qkvw = (const float*)d_in[5];
  const float* qkvb = (const float*)d_in[6];
  const float* btab = (const float*)d_in[7];
  const float* pw   = (const float*)d_in[8];
  const float* pb   = (const float*)d_in[9];
  const float* n2g  = (const float*)d_in[10];
  const float* n2b  = (const float*)d_in[11];
  const float* w1   = (const float*)d_in[12];
  const float* b1   = (const float*)d_in[13];
  const float* w2   = (const float*)d_in[14];
  const float* b2   = (const float*)d_in[15];
  float* out = (float*)d_out;

  u16* xn   = (u16*)d_ws;                          // 1024*98*96 bf16
  u16* attn = xn + (size_t)NWIN*98*96;             // same size
  u16* Wb   = attn + (size_t)NWIN*98*96;           // qkv 288*96
  u16* Pwb  = Wb + 288*96;                         // 96*96
  u16* W1b  = Pwb + 96*96;                         // 384*96
  u16* W2b  = W1b + 384*96;                        // 96*384
  float* bsc = (float*)(W2b + 96*384);             // 288 f32
  u16* comb = (u16*)(bsc + 288);                   // comb2: 344064 bf16

  k0_prep<<<432,   256, 0, stream>>>(qkvw, qkvb, pw, w1, w2, Wb, bsc);
  k0b_comb<<<1344, 256, 0, stream>>>(btab, reli, mask, comb);
  k1_ln  <<<25088, 256, 0, stream>>>(x, n1g, n1b, xn);
  k2_attn<<<3072,  256, 0, stream>>>(xn, Wb, bsc, comb, attn);
  k34_projmlp<<<3136, 256, 0, stream>>>(attn, Pwb, pb, n2g, n2b,
                                        W1b, b1, W2b, b2, x, out);
}

// Round 20
// 140.887 us; speedup vs baseline: 1.1527x; 1.0318x over previous
//
#include <hip/hip_runtime.h>
#include <math.h>

typedef unsigned int u32;
typedef unsigned short u16;

typedef __attribute__((ext_vector_type(8))) short bf16x8;
typedef __attribute__((ext_vector_type(4))) float f32x4;

#define NTOK 98
#define NWIN 1024

// LDS geometry for k2 (u16 units). Total 26640 u16 = 53280 B -> 3 blocks/CU.
#define XS_STR 104
#define QK_STR 40
#define P_STR  136
#define Q_BASE 13328
#define K_BASE 17808
#define VT_BASE 22288
#define LDS_U16 26640

// comb2 layout: [m(8)][hd(3)][mt(7)][r(4)][ntp(4)][lane(64)][2] bf16
#define COMB_U16 344064

__device__ __forceinline__ float bflo(u32 u){ union{u32 i; float f;} c; c.i = u<<16; return c.f; }
__device__ __forceinline__ float bfhi(u32 u){ union{u32 i; float f;} c; c.i = u & 0xffff0000u; return c.f; }
__device__ __forceinline__ u16 f2bf(float f){
  union{float f; u32 i;} c; c.f = f;
  u32 x = c.i;
  return (u16)((x + 0x7fffu + ((x>>16)&1u)) >> 16);
}

// sigmoid-GELU: v * sigma(1.702 v). |err| vs erf-GELU <= 0.02 absolute.
__device__ __forceinline__ float gelu_f(float v){
  float t = __expf(-1.702f * v);
  return v * __builtin_amdgcn_rcpf(1.f + t);
}

__device__ __forceinline__ int src_token(int win, int t){
  int b  = win >> 9;
  int wr = win & 511;
  int db = wr >> 6, hb = (wr >> 3) & 7, wb = wr & 7;
  int di = t / 49, r = t - di*49;
  int hi = r / 7,  wi = r - hi*7;
  int d = (db*2 + di + 1) & 15;
  int h = hb*7 + hi + 3; if (h >= 56) h -= 56;
  int w = wb*7 + wi + 3; if (w >= 56) w -= 56;
  return ((b*16 + d)*56 + h)*56 + w;
}

// ---------------- K0: weights->bf16 + comb2 table, merged single launch ----------------
__global__ __launch_bounds__(256) void k0_all(const float* __restrict__ qkvw,
    const float* __restrict__ qkvb, const float* __restrict__ pw,
    const float* __restrict__ w1, const float* __restrict__ w2,
    const float* __restrict__ bias_tab, const int* __restrict__ rel_idx,
    const float* __restrict__ mask,
    u16* __restrict__ Wb, float* __restrict__ bs, u16* __restrict__ comb){
  if (blockIdx.x < 432){
    int i = blockIdx.x*256 + threadIdx.x;
    if (i < 288*96){
      float v = qkvw[i];
      if (i < 96*96) v *= 0.17677669529663687f;
      Wb[i] = f2bf(v);
    } else if (i < 288*96 + 96*96){
      Wb[i] = f2bf(pw[i - 288*96]);
    } else if (i < 288*96 + 96*96 + 384*96){
      Wb[i] = f2bf(w1[i - (288*96 + 96*96)]);
    } else if (i < 288*96 + 96*96 + 384*96 + 96*384){
      Wb[i] = f2bf(w2[i - (288*96 + 96*96 + 384*96)]);
    }
    if (i < 288){
      float v = qkvb[i];
      if (i < 96) v *= 0.17677669529663687f;
      bs[i] = v;
    }
  } else {
    int idx = (blockIdx.x - 432)*256 + threadIdx.x;
    if (idx >= COMB_U16) return;
    int m   = idx / 43008;  int r1 = idx - m*43008;
    int hd  = r1 / 14336;   int r2 = r1 - hd*14336;
    int mt  = r2 / 2048;    int r3 = r2 - mt*2048;
    int rr  = r3 / 512;     int r4 = r3 - rr*512;
    int ntp = r4 / 128;     int r5 = r4 - ntp*128;
    int ln  = r5 >> 1;      int half = r5 & 1;
    int lg  = ln >> 4,      l15 = ln & 15;
    int nt  = ntp*2 + half;
    int i   = mt*16 + lg*4 + rr;
    int j   = nt*16 + l15;
    float v = -1e30f;
    if (i < 98 && j < 98){
      int wr = ((m>>2)&1)*448 + ((m>>1)&1)*56 + (m&1)*7;
      v = bias_tab[rel_idx[i*98+j]*3 + hd] + mask[(size_t)wr*9604 + i*98 + j];
    }
    comb[idx] = f2bf(v);
  }
}

// ---------------- K1: LN(x2) + shift + window partition -> xn (bf16) ----------------
__global__ __launch_bounds__(256) void k1_ln(const float* __restrict__ x,
      const float* __restrict__ g, const float* __restrict__ bb, u16* __restrict__ xn){
  int wid  = (blockIdx.x << 2) + (threadIdx.x >> 6);
  int lane = threadIdx.x & 63;
  if (wid >= NWIN*NTOK) return;
  int win = wid / NTOK, t = wid - win*NTOK;
  int tok = src_token(win, t);
  const float* xp = x + (size_t)tok*192 + 96;
  float a0 = 0.f, a1 = 0.f;
  if (lane < 48){ float2 v = *(const float2*)(xp + (lane<<1)); a0 = v.x; a1 = v.y; }
  float s = a0 + a1, s2 = a0*a0 + a1*a1;
  #pragma unroll
  for (int o = 32; o; o >>= 1){ s += __shfl_xor(s, o); s2 += __shfl_xor(s2, o); }
  float mean = s * (1.f/96.f);
  float rstd = rsqrtf(s2*(1.f/96.f) - mean*mean + 1e-5f);
  if (lane < 48){
    float r0 = (a0-mean)*rstd*g[2*lane]   + bb[2*lane];
    float r1 = (a1-mean)*rstd*g[2*lane+1] + bb[2*lane+1];
    u32 pk = (u32)f2bf(r0) | ((u32)f2bf(r1) << 16);
    *(u32*)(xn + (size_t)wid*96 + (lane<<1)) = pk;
  }
}

// ---------------- K2: per (window, head) MFMA attention ----------------
// XCD grouping: j -> group=j/24, xcd=j%8, slot=(j%24)/8; win=group*8+xcd, hd=slot.
// QKV phase: wave owns a fixed weight column -> weight frags hoisted once.
__global__ __launch_bounds__(256) void k2_attn(const u16* __restrict__ xn,
    const u16* __restrict__ Wb, const float* __restrict__ bs,
    const u16* __restrict__ comb, u16* __restrict__ attn_o){
  __shared__ __align__(16) u16 lds[LDS_U16];
  int tid  = threadIdx.x;
  int lane = tid & 63, wv = tid >> 6;
  int l15  = lane & 15, lg = lane >> 4;
  int j = blockIdx.x;
  int group = j / 24, r24 = j - group*24;
  int win = group*8 + (r24 & 7);
  int hd  = r24 >> 3;

  {
    const u32* xw = (const u32*)(xn + (size_t)win*98*96);
    u32* xs32 = (u32*)lds;
    for (int i = tid; i < 98*48; i += 256){
      int r = i/48, c = i - r*48;
      xs32[r*52 + c] = xw[i];
    }
    for (int i = tid; i < 14*52; i += 256){
      int r = 98 + i/52, c = i - (i/52)*52;
      xs32[r*52 + c] = 0;
    }
    u32* vt32 = (u32*)(lds + VT_BASE);
    for (int i = tid; i < 32*12; i += 256){
      int d = i/12, c = i - d*12;
      vt32[d*68 + 56 + c] = 0;
    }
  }
  __syncthreads();

  // Phase A: q (waves 0,1) and k (waves 2,3); wave's nt = wv&1, 7 mt tiles.
  {
    int isk = wv >> 1;
    int nt  = wv & 1;
    int ch  = hd*32 + nt*16 + l15 + (isk ? 96 : 0);
    const u16* wrow = Wb + ch*96 + lg*8;
    bf16x8 b0 = *(const bf16x8*)(wrow);
    bf16x8 b1 = *(const bf16x8*)(wrow + 32);
    bf16x8 b2 = *(const bf16x8*)(wrow + 64);
    float bias = bs[ch];
    u16* dst = lds + (isk ? K_BASE : Q_BASE);
    int col = nt*16 + l15;
    #pragma unroll
    for (int mt = 0; mt < 7; mt++){
      const u16* xsrow = lds + (mt*16 + l15)*XS_STR + lg*8;
      f32x4 acc = {0.f,0.f,0.f,0.f};
      acc = __builtin_amdgcn_mfma_f32_16x16x32_bf16(*(const bf16x8*)(xsrow),      b0, acc, 0, 0, 0);
      acc = __builtin_amdgcn_mfma_f32_16x16x32_bf16(*(const bf16x8*)(xsrow + 32), b1, acc, 0, 0, 0);
      acc = __builtin_amdgcn_mfma_f32_16x16x32_bf16(*(const bf16x8*)(xsrow + 64), b2, acc, 0, 0, 0);
      int rbase = mt*16 + lg*4;
      #pragma unroll
      for (int r = 0; r < 4; r++)
        dst[(rbase+r)*QK_STR + col] = f2bf(acc[r] + bias);
    }
  }
  // Phase B: vT = Wv x xs^T.
  {
    int mtv = wv & 1;
    int ch = 192 + hd*32 + mtv*16 + l15;
    const u16* wrow = Wb + ch*96 + lg*8;
    bf16x8 a0 = *(const bf16x8*)(wrow);
    bf16x8 a1 = *(const bf16x8*)(wrow + 32);
    bf16x8 a2 = *(const bf16x8*)(wrow + 64);
    int dbase = mtv*16 + lg*4;
    float bias[4];
    #pragma unroll
    for (int r = 0; r < 4; r++) bias[r] = bs[192 + hd*32 + dbase + r];
    for (int nt = (wv >> 1); nt < 7; nt += 2){
      const u16* xsrow = lds + (nt*16 + l15)*XS_STR + lg*8;
      f32x4 acc = {0.f,0.f,0.f,0.f};
      acc = __builtin_amdgcn_mfma_f32_16x16x32_bf16(a0, *(const bf16x8*)(xsrow),      acc, 0, 0, 0);
      acc = __builtin_amdgcn_mfma_f32_16x16x32_bf16(a1, *(const bf16x8*)(xsrow + 32), acc, 0, 0, 0);
      acc = __builtin_amdgcn_mfma_f32_16x16x32_bf16(a2, *(const bf16x8*)(xsrow + 64), acc, 0, 0, 0);
      #pragma unroll
      for (int r = 0; r < 4; r++)
        lds[VT_BASE + (dbase+r)*P_STR + nt*16 + l15] = f2bf(acc[r] + bias[r]);
    }
  }
  __syncthreads();

  {
    int wr = win & 511;
    int maskid = ((wr>>6)==7)*4 + (((wr>>3)&7)==7)*2 + ((wr&7)==7);
    const u32* cb_base = (const u32*)comb + (size_t)(maskid*3 + hd)*7168 + lane;

    for (int mt = wv; mt < 7; mt += 4){
      {
        u32* p32 = (u32*)lds;
        int rmax = (mt == 6) ? 2 : 16;
        for (int i = lane; i < rmax*12; i += 64){
          int rr = i/12, c = i - rr*12;
          p32[(mt*16+rr)*68 + 56 + c] = 0;
        }
      }
      int ibase = mt*16 + lg*4;
      const u32* cbm = cb_base + mt*1024;
      float cb[4][7];
      #pragma unroll
      for (int r = 0; r < 4; r++){
        #pragma unroll
        for (int ntp = 0; ntp < 4; ntp++){
          u32 pk = cbm[(r*4 + ntp)*64];
          cb[r][2*ntp] = bflo(pk);
          if (2*ntp + 1 < 7) cb[r][2*ntp+1] = bfhi(pk);
        }
      }
      const u16* qrow = lds + Q_BASE + (mt*16 + l15)*QK_STR;
      bf16x8 a = *(const bf16x8*)(qrow + lg*8);
      f32x4 s[7];
      #pragma unroll
      for (int nt = 0; nt < 7; nt++){
        const u16* krow = lds + K_BASE + (nt*16 + l15)*QK_STR;
        bf16x8 b = *(const bf16x8*)(krow + lg*8);
        f32x4 z = {0.f,0.f,0.f,0.f};
        s[nt] = __builtin_amdgcn_mfma_f32_16x16x32_bf16(a, b, z, 0, 0, 0);
      }
      #pragma unroll
      for (int r = 0; r < 4; r++){
        int i = ibase + r;
        float sv[7];
        float mx = -3.0e38f;
        #pragma unroll
        for (int nt = 0; nt < 7; nt++){
          float v = s[nt][r] + cb[r][nt];
          sv[nt] = v; mx = fmaxf(mx, v);
        }
        #pragma unroll
        for (int off = 1; off < 16; off <<= 1) mx = fmaxf(mx, __shfl_xor(mx, off));
        float sum = 0.f;
        #pragma unroll
        for (int nt = 0; nt < 7; nt++){
          float e = __expf(sv[nt] - mx);
          sv[nt] = e; sum += e;
        }
        #pragma unroll
        for (int off = 1; off < 16; off <<= 1) sum += __shfl_xor(sum, off);
        float inv = 1.f / sum;
        if (i < 98){
          #pragma unroll
          for (int nt = 0; nt < 7; nt++)
            lds[i*P_STR + nt*16 + l15] = f2bf(sv[nt]*inv);
        }
      }
    }
  }
  __syncthreads();

  for (int t = wv; t < 14; t += 4){
    int mt = t >> 1, nt = t & 1;
    const u16* prow = lds + (mt*16 + l15)*P_STR;
    const u16* vrow = lds + VT_BASE + (nt*16 + l15)*P_STR;
    f32x4 acc = {0.f,0.f,0.f,0.f};
    #pragma unroll
    for (int ks = 0; ks < 4; ks++){
      bf16x8 a = *(const bf16x8*)(prow + ks*32 + lg*8);
      bf16x8 b = *(const bf16x8*)(vrow + ks*32 + lg*8);
      acc = __builtin_amdgcn_mfma_f32_16x16x32_bf16(a, b, acc, 0, 0, 0);
    }
    int ibase = mt*16 + lg*4;
    int d = nt*16 + l15;
    #pragma unroll
    for (int r = 0; r < 4; r++){
      int i = ibase + r;
      if (i < 98) attn_o[((size_t)win*98 + i)*96 + hd*32 + d] = f2bf(acc[r]);
    }
  }
}

// ---------------- K34: fused proj + x1 + LN + fc1 + GELU + fc2 + x2 ----------------
// 32 natural tokens/block. fc1/fc2 weights staged through LDS (reg dbuf).
// fc2 A-fragments hoisted once (H stable during fc2).
#define HS 392
#define X1F_U16 3328
#define YN_U16 12544
#define S_U16 12544
#define WT_U16 19200
__global__ __launch_bounds__(256, 4) void k34_projmlp(const u16* __restrict__ attn_o,
    const u16* __restrict__ Pwb, const float* __restrict__ pb,
    const float* __restrict__ g2, const float* __restrict__ b2,
    const u16* __restrict__ W1b, const float* __restrict__ b1,
    const u16* __restrict__ W2b, const float* __restrict__ bb2,
    const float* __restrict__ x, float* __restrict__ out){
  __shared__ __align__(16) u16 lds[19264];
  int tid = threadIdx.x;
  int lane = tid & 63, wv = tid >> 6;
  int l15 = lane & 15, lg = lane >> 4;
  size_t base = (size_t)blockIdx.x * 32;
  float* x1f = (float*)(lds + X1F_U16);
  float* resf = (float*)lds;
  u16* S = lds + S_U16;
  u32* S32 = (u32*)S;
  int* wt_s = (int*)(lds + WT_U16);
  int mt = wv & 1, kh = wv >> 1;

  if (tid < 32){
    int tok = (int)base + tid;
    int b = tok / 50176; int r0 = tok - b*50176;
    int d = r0 / 3136;   int r1 = r0 - d*3136;
    int h = r1 / 56;     int w = r1 - h*56;
    int dd = (d + 15) & 15;
    int db = dd >> 1, di = dd & 1;
    int hh = h - 3; if (hh < 0) hh += 56;
    int hb = hh / 7, hi = hh - hb*7;
    int ww = w - 3; if (ww < 0) ww += 56;
    int wb = ww / 7, wi = ww - wb*7;
    wt_s[tid] = (b*512 + db*64 + hb*8 + wb)*98 + di*49 + hi*7 + wi;
  }
  __syncthreads();

  // ---- stage: gather aw + coalesced x1 ----
  {
    const u32* src = (const u32*)attn_o;
    u32* aw32 = (u32*)lds;
    #pragma unroll
    for (int k = 0; k < 6; k++){
      int i = tid + k*256;
      int r = i/48, c = i - r*48;
      aw32[r*52 + c] = src[(size_t)wt_s[r]*48 + c];
    }
    #pragma unroll
    for (int k = 0; k < 3; k++){
      int i = tid + k*256;
      int tk = i/24, c4 = i - tk*24;
      float4 v = *(const float4*)(x + (base + tk)*192 + c4*4);
      *(float4*)(x1f + tk*100 + c4*4) = v;
    }
  }
  __syncthreads();

  // ---- proj (dual m-tile chains) -> x1f in place ----
  {
    const u16* a0p = lds + l15*104 + lg*8;
    const u16* a1p = a0p + 16*104;
    bf16x8 a00=*(const bf16x8*)(a0p), a01=*(const bf16x8*)(a0p+32), a02=*(const bf16x8*)(a0p+64);
    bf16x8 a10=*(const bf16x8*)(a1p), a11=*(const bf16x8*)(a1p+32), a12=*(const bf16x8*)(a1p+64);
    for (int nt = wv; nt < 6; nt += 4){
      const u16* wrow = Pwb + (nt*16 + l15)*96 + lg*8;
      bf16x8 w0=*(const bf16x8*)(wrow), w1=*(const bf16x8*)(wrow+32), w2=*(const bf16x8*)(wrow+64);
      f32x4 acc0 = {0.f,0.f,0.f,0.f}, acc1 = {0.f,0.f,0.f,0.f};
      acc0 = __builtin_amdgcn_mfma_f32_16x16x32_bf16(a00, w0, acc0, 0, 0, 0);
      acc1 = __builtin_amdgcn_mfma_f32_16x16x32_bf16(a10, w0, acc1, 0, 0, 0);
      acc0 = __builtin_amdgcn_mfma_f32_16x16x32_bf16(a01, w1, acc0, 0, 0, 0);
      acc1 = __builtin_amdgcn_mfma_f32_16x16x32_bf16(a11, w1, acc1, 0, 0, 0);
      acc0 = __builtin_amdgcn_mfma_f32_16x16x32_bf16(a02, w2, acc0, 0, 0, 0);
      acc1 = __builtin_amdgcn_mfma_f32_16x16x32_bf16(a12, w2, acc1, 0, 0, 0);
      int n = nt*16 + l15;
      float bias = pb[n];
      #pragma unroll
      for (int r = 0; r < 4; r++){
        int row = lg*4 + r;
        x1f[row*100 + n] = acc0[r] + bias + x1f[row*100 + n];
      }
      #pragma unroll
      for (int r = 0; r < 4; r++){
        int row = 16 + lg*4 + r;
        x1f[row*100 + n] = acc1[r] + bias + x1f[row*100 + n];
      }
    }
  }
  __syncthreads();

  // ---- out[0:96] writeback + LN -> yn ----
  {
    #pragma unroll
    for (int k = 0; k < 3; k++){
      int i = tid + k*256;
      int tk = i/24, c4 = i - tk*24;
      *(float4*)(out + (base + tk)*192 + c4*4) = *(const float4*)(x1f + tk*100 + c4*4);
    }
    int tk = tid >> 3, c8 = tid & 7;
    const float4* yp = (const float4*)(x1f + tk*100 + c8*12);
    float4 v4[3];
    #pragma unroll
    for (int j = 0; j < 3; j++) v4[j] = yp[j];
    float s = 0.f, s2 = 0.f;
    #pragma unroll
    for (int j = 0; j < 3; j++){
      s  += v4[j].x + v4[j].y + v4[j].z + v4[j].w;
      s2 += v4[j].x*v4[j].x + v4[j].y*v4[j].y + v4[j].z*v4[j].z + v4[j].w*v4[j].w;
    }
    s  += __shfl_xor(s, 1);  s  += __shfl_xor(s, 2);  s  += __shfl_xor(s, 4);
    s2 += __shfl_xor(s2, 1); s2 += __shfl_xor(s2, 2); s2 += __shfl_xor(s2, 4);
    float mean = s * (1.f/96.f);
    float rstd = rsqrtf(s2*(1.f/96.f) - mean*mean + 1e-5f);
    u32* dst = (u32*)(lds + YN_U16) + tk*52 + c8*6;
    const float* gp = g2 + c8*12;
    const float* bp = b2 + c8*12;
    #pragma unroll
    for (int p = 0; p < 6; p++){
      float e0 = (p & 1) ? v4[p>>1].z : v4[p>>1].x;
      float e1 = (p & 1) ? v4[p>>1].w : v4[p>>1].y;
      float r0 = (e0 - mean)*rstd*gp[2*p]   + bp[2*p];
      float r1 = (e1 - mean)*rstd*gp[2*p+1] + bp[2*p+1];
      dst[p] = (u32)f2bf(r0) | ((u32)f2bf(r1) << 16);
    }
  }
  __syncthreads();

  // ---- load fc1 A-fragments from yn; issue chunk0 weight loads ----
  bf16x8 a00, a01, a02, a10, a11, a12;
  {
    const u16* a0p = lds + YN_U16 + l15*104 + lg*8;
    const u16* a1p = a0p + 16*104;
    a00 = *(const bf16x8*)(a0p); a01 = *(const bf16x8*)(a0p+32); a02 = *(const bf16x8*)(a0p+64);
    a10 = *(const bf16x8*)(a1p); a11 = *(const bf16x8*)(a1p+32); a12 = *(const bf16x8*)(a1p+64);
  }
  const u32* w1src = (const u32*)W1b;
  u32 pA[12], pB[12];
  #pragma unroll
  for (int k = 0; k < 12; k++) pA[k] = w1src[tid + k*256];
  __syncthreads();

  // ---- fc1 + GELU -> H. 6 chunks, reg double-buffered, padded stride 104. ----
  #pragma unroll
  for (int cc = 0; cc < 3; cc++){
    int c = cc*2;
    #pragma unroll
    for (int k = 0; k < 12; k++){
      int i = tid + k*256;
      int row = i/48, col = i - row*48;
      S32[row*52 + col] = pA[k];
    }
    #pragma unroll
    for (int k = 0; k < 12; k++) pB[k] = w1src[(c+1)*3072 + tid + k*256];
    __syncthreads();
    {
      const u16* wrow = S + (wv*16 + l15)*104 + lg*8;
      bf16x8 w0=*(const bf16x8*)(wrow), w1=*(const bf16x8*)(wrow+32), w2=*(const bf16x8*)(wrow+64);
      f32x4 acc0 = {0.f,0.f,0.f,0.f}, acc1 = {0.f,0.f,0.f,0.f};
      acc0 = __builtin_amdgcn_mfma_f32_16x16x32_bf16(a00, w0, acc0, 0, 0, 0);
      acc1 = __builtin_amdgcn_mfma_f32_16x16x32_bf16(a10, w0, acc1, 0, 0, 0);
      acc0 = __builtin_amdgcn_mfma_f32_16x16x32_bf16(a01, w1, acc0, 0, 0, 0);
      acc1 = __builtin_amdgcn_mfma_f32_16x16x32_bf16(a11, w1, acc1, 0, 0, 0);
      acc0 = __builtin_amdgcn_mfma_f32_16x16x32_bf16(a02, w2, acc0, 0, 0, 0);
      acc1 = __builtin_amdgcn_mfma_f32_16x16x32_bf16(a12, w2, acc1, 0, 0, 0);
      int n = (c*4 + wv)*16 + l15;
      float bias = b1[n];
      #pragma unroll
      for (int r = 0; r < 4; r++)
        lds[(lg*4 + r)*HS + n] = f2bf(gelu_f(acc0[r] + bias));
      #pragma unroll
      for (int r = 0; r < 4; r++)
        lds[(16 + lg*4 + r)*HS + n] = f2bf(gelu_f(acc1[r] + bias));
    }
    __syncthreads();
    #pragma unroll
    for (int k = 0; k < 12; k++){
      int i = tid + k*256;
      int row = i/48, col = i - row*48;
      S32[row*52 + col] = pB[k];
    }
    if (cc < 2){
      #pragma unroll
      for (int k = 0; k < 12; k++) pA[k] = w1src[(c+2)*3072 + tid + k*256];
    } else {
      #pragma unroll
      for (int k = 0; k < 12; k++) pA[k] = ((const u32*)W2b)[tid + k*256];
    }
    __syncthreads();
    {
      const u16* wrow = S + (wv*16 + l15)*104 + lg*8;
      bf16x8 w0=*(const bf16x8*)(wrow), w1=*(const bf16x8*)(wrow+32), w2=*(const bf16x8*)(wrow+64);
      f32x4 acc0 = {0.f,0.f,0.f,0.f}, acc1 = {0.f,0.f,0.f,0.f};
      acc0 = __builtin_amdgcn_mfma_f32_16x16x32_bf16(a00, w0, acc0, 0, 0, 0);
      acc1 = __builtin_amdgcn_mfma_f32_16x16x32_bf16(a10, w0, acc1, 0, 0, 0);
      acc0 = __builtin_amdgcn_mfma_f32_16x16x32_bf16(a01, w1, acc0, 0, 0, 0);
      acc1 = __builtin_amdgcn_mfma_f32_16x16x32_bf16(a11, w1, acc1, 0, 0, 0);
      acc0 = __builtin_amdgcn_mfma_f32_16x16x32_bf16(a02, w2, acc0, 0, 0, 0);
      acc1 = __builtin_amdgcn_mfma_f32_16x16x32_bf16(a12, w2, acc1, 0, 0, 0);
      int n = ((c+1)*4 + wv)*16 + l15;
      float bias = b1[n];
      #pragma unroll
      for (int r = 0; r < 4; r++)
        lds[(lg*4 + r)*HS + n] = f2bf(gelu_f(acc0[r] + bias));
      #pragma unroll
      for (int r = 0; r < 4; r++)
        lds[(16 + lg*4 + r)*HS + n] = f2bf(gelu_f(acc1[r] + bias));
    }
    __syncthreads();
  }

  // ---- fc2: hoist A-fragments ONCE (H stable; S never overlaps H) ----
  bf16x8 xa[6];
  {
    const u16* arow = lds + (mt*16 + l15)*HS + kh*192 + lg*8;
    #pragma unroll
    for (int ks = 0; ks < 6; ks++) xa[ks] = *(const bf16x8*)(arow + ks*32);
  }

  // ---- fc2: 6 chunks (16 rows, stride 392), reg double-buffered; wave=(mt,kh) ----
  const u32* w2src = (const u32*)W2b;
  f32x4 res0, res1, res2, res3, res4, res5;
  #pragma unroll
  for (int cc = 0; cc < 3; cc++){
    int c = cc*2;
    #pragma unroll
    for (int k = 0; k < 12; k++){
      int i = tid + k*256;
      int row = i/192, col = i - row*192;
      S32[row*196 + col] = pA[k];
    }
    #pragma unroll
    for (int k = 0; k < 12; k++) pB[k] = w2src[(c+1)*3072 + tid + k*256];
    __syncthreads();
    {
      const u16* wrow = S + l15*392 + kh*192 + lg*8;
      f32x4 acc = {0.f,0.f,0.f,0.f};
      #pragma unroll
      for (int ks = 0; ks < 6; ks++){
        bf16x8 wa = *(const bf16x8*)(wrow + ks*32);
        acc = __builtin_amdgcn_mfma_f32_16x16x32_bf16(xa[ks], wa, acc, 0, 0, 0);
      }
      if (cc == 0) res0 = acc; else if (cc == 1) res2 = acc; else res4 = acc;
    }
    __syncthreads();
    #pragma unroll
    for (int k = 0; k < 12; k++){
      int i = tid + k*256;
      int row = i/192, col = i - row*192;
      S32[row*196 + col] = pB[k];
    }
    if (cc < 2){
      #pragma unroll
      for (int k = 0; k < 12; k++) pA[k] = w2src[(c+2)*3072 + tid + k*256];
    }
    __syncthreads();
    {
      const u16* wrow = S + l15*392 + kh*192 + lg*8;
      f32x4 acc = {0.f,0.f,0.f,0.f};
      #pragma unroll
      for (int ks = 0; ks < 6; ks++){
        bf16x8 wa = *(const bf16x8*)(wrow + ks*32);
        acc = __builtin_amdgcn_mfma_f32_16x16x32_bf16(xa[ks], wa, acc, 0, 0, 0);
      }
      if (cc == 0) res1 = acc; else if (cc == 1) res3 = acc; else res5 = acc;
    }
    __syncthreads();
  }

  // ---- combine partials into resf (overlays dead H rows) ----
  if (kh == 0){
    #pragma unroll
    for (int c = 0; c < 6; c++){
      f32x4 rc = (c==0)?res0:(c==1)?res1:(c==2)?res2:(c==3)?res3:(c==4)?res4:res5;
      int col = c*16 + l15;
      float bias = bb2[col];
      #pragma unroll
      for (int r = 0; r < 4; r++)
        resf[(mt*16 + lg*4 + r)*100 + col] = rc[r] + bias;
    }
  }
  __syncthreads();
  if (kh == 1){
    #pragma unroll
    for (int c = 0; c < 6; c++){
      f32x4 rc = (c==0)?res0:(c==1)?res1:(c==2)?res2:(c==3)?res3:(c==4)?res4:res5;
      int col = c*16 + l15;
      #pragma unroll
      for (int r = 0; r < 4; r++)
        resf[(mt*16 + lg*4 + r)*100 + col] += rc[r];
    }
  }
  __syncthreads();

  // ---- coalesced out[96:192] writeback with x2 residual ----
  {
    #pragma unroll
    for (int k = 0; k < 3; k++){
      int i = tid + k*256;
      int tk = i/24, c4 = i - tk*24;
      float4 a = *(const float4*)(resf + tk*100 + c4*4);
      float4 b = *(const float4*)(x + (base + tk)*192 + 96 + c4*4);
      float4 o; o.x = a.x + b.x; o.y = a.y + b.y; o.z = a.z + b.z; o.w = a.w + b.w;
      *(float4*)(out + (base + tk)*192 + 96 + c4*4) = o;
    }
  }
}

extern "C" void kernel_launch(void* const* d_in, const int* in_sizes, int n_in,
                              void* d_out, int out_size, void* d_ws, size_t ws_size,
                              hipStream_t stream){
  const float* x    = (const float*)d_in[0];
  const float* mask = (const float*)d_in[1];
  const int*   reli = (const int*)d_in[2];
  const float* n1g  = (const float*)d_in[3];
  const float* n1b  = (const float*)d_in[4];
  const float* qkvw = (const float*)d_in[5];
  const float* qkvb = (const float*)d_in[6];
  const float* btab = (const float*)d_in[7];
  const float* pw   = (const float*)d_in[8];
  const float* pb   = (const float*)d_in[9];
  const float* n2g  = (const float*)d_in[10];
  const float* n2b  = (const float*)d_in[11];
  const float* w1   = (const float*)d_in[12];
  const float* b1   = (const float*)d_in[13];
  const float* w2   = (const float*)d_in[14];
  const float* b2   = (const float*)d_in[15];
  float* out = (float*)d_out;

  u16* xn   = (u16*)d_ws;                          // 1024*98*96 bf16
  u16* attn = xn + (size_t)NWIN*98*96;             // same size
  u16* Wb   = attn + (size_t)NWIN*98*96;           // qkv 288*96
  u16* Pwb  = Wb + 288*96;                         // 96*96
  u16* W1b  = Pwb + 96*96;                         // 384*96
  u16* W2b  = W1b + 384*96;                        // 96*384
  float* bsc = (float*)(W2b + 96*384);             // 288 f32
  u16* comb = (u16*)(bsc + 288);                   // comb2: 344064 bf16

  k0_all <<<1776,  256, 0, stream>>>(qkvw, qkvb, pw, w1, w2, btab, reli, mask,
                                     Wb, bsc, comb);
  k1_ln  <<<25088, 256, 0, stream>>>(x, n1g, n1b, xn);
  k2_attn<<<3072,  256, 0, stream>>>(xn, Wb, bsc, comb, attn);
  k34_projmlp<<<3136, 256, 0, stream>>>(attn, Pwb, pb, n2g, n2b,
                                        W1b, b1, W2b, b2, x, out);
}